// Round 10
// baseline (418.560 us; speedup 1.0000x reference)
//
#include <hip/hip_runtime.h>

typedef unsigned short u16;
typedef __bf16 bf16x8 __attribute__((ext_vector_type(8)));
typedef float f32x4 __attribute__((ext_vector_type(4)));
typedef unsigned short u16x8 __attribute__((ext_vector_type(8)));
typedef unsigned short u16x4 __attribute__((ext_vector_type(4)));

#define MFMA16(A,B,C) __builtin_amdgcn_mfma_f32_16x16x32_bf16(A,B,C,0,0,0)

__device__ __forceinline__ float b2f(u16 h){ unsigned u = ((unsigned)h)<<16; return __builtin_bit_cast(float,u); }
__device__ __forceinline__ u16 f2b(float f){ unsigned u = __builtin_bit_cast(unsigned,f); u += 0x7fffu + ((u>>16)&1u); return (u16)(u>>16); }
__device__ __forceinline__ bf16x8 ldb8(const u16* p){ return __builtin_bit_cast(bf16x8, *(const u16x8*)p); }

// async global->LDS, 16B per lane; LDS dest = wave-uniform base + lane*16.
__device__ __forceinline__ void g2lds16(const u16* g, u16* l){
  __builtin_amdgcn_global_load_lds((const __attribute__((address_space(1))) void*)g,
                                   (__attribute__((address_space(3))) void*)l, 16, 0, 0);
}

#define BAR   __builtin_amdgcn_s_barrier()
#define VMC8  asm volatile("s_waitcnt vmcnt(8)" ::: "memory")
#define VMC4  asm volatile("s_waitcnt vmcnt(4)" ::: "memory")
#define VMC0  asm volatile("s_waitcnt vmcnt(0)" ::: "memory")

// B=16, C=256, H=W=64, NH=8, DH=64, POS_C=4.  4096 px/batch.
// fp32 inputs/output; bf16 internal.  CB batches/chunk from ws_size.
// K extended 256->320 (cols 256..259 = pos, 260..319 = 0) = 10 x BK=32.
// R9: K-TILED staging layouts.  XT2[t][npix][32], WP2[t][1536][32] -- each
// phase's 128x32 panel is 8 KB CONTIGUOUS, so every g2lds call fetches 8
// full aligned 128-B lines (R2-R8's row-major-320 layouts split every L2
// line across two phases and doubled the request count; all five schedule
// variants plateaued at 60-68 us on that same address pattern).
// Layouts: Q,K,V ALL [bl][h][p][d]; U [bl][h][p][d].
// V^T is built per-plane-slice inside k_attn.

// ---------------------------------------------------------------------------
// Weight prep: WP2[t][1536][32] (k-tiled; k 256..259 = pos weights, rest 0),
// BIAS[1536], WoP[256][512] (bf16).
__global__ void k_prep_w(const float* __restrict__ Wq, const float* __restrict__ Wk,
                         const float* __restrict__ Wv, const float* __restrict__ bq,
                         const float* __restrict__ bk, const float* __restrict__ bv,
                         const float* __restrict__ Wo,
                         u16* __restrict__ WP, u16* __restrict__ BIAS,
                         u16* __restrict__ WoP){
  int r = blockIdx.x;                 // 0..1791
  int tid = threadIdx.x;
  if (r < 1536){
    int t = r >> 9, rm = r & 511;
    const float* src = (t==0 ? Wq : (t==1 ? Wk : Wv)) + (long)rm*260;
    WP[((long)(tid>>5)*1536 + r)*32 + (tid&31)] = f2b(src[tid]);
    if (tid < 64){
      int c = 256 + tid;
      WP[((long)(c>>5)*1536 + r)*32 + (c&31)] = (tid < 4) ? f2b(src[256 + tid]) : (u16)0;
    }
    if (tid == 0){
      const float* bs = (t==0 ? bq : (t==1 ? bk : bv));
      BIAS[r] = f2b(bs[rm]);
    }
  } else {
    int co = r - 1536;
    WoP[(long)co*512 + tid]       = f2b(Wo[(long)co*512 + tid]);
    WoP[(long)co*512 + 256 + tid] = f2b(Wo[(long)co*512 + 256 + tid]);
  }
}

// Diagnostic: ws too small -> fill out with 100.0f.
__global__ void k_sentinel(float* __restrict__ out){
  long i = (long)blockIdx.x*256 + threadIdx.x;
  out[i] = 100.0f;
}

// ---------------------------------------------------------------------------
// x [gb][c][4096] fp32 -> XT2[t][npix][32] bf16 (transpose + convert,
// k-tiled).  ct==0 blocks also write the pos tail (t=8,9).
__global__ __launch_bounds__(256) void k_cvtx(const float* __restrict__ x,
                                              const float* __restrict__ pos,
                                              u16* __restrict__ XT, int b0, int npix){
  __shared__ u16 tile[64*65];
  int bidx = blockIdx.x;
  int ct = bidx & 3, pt = (bidx>>2)&63, bl = bidx>>8;
  int c0 = ct*64, p0 = pt*64;
  int tid = threadIdx.x;
  const float* xb = x + (long)(b0+bl)*256*4096;
  #pragma unroll
  for (int it=0; it<16; ++it){
    int idx = it*256 + tid; int cc = idx>>6, px = idx&63;
    tile[cc*65 + px] = f2b(xb[(long)(c0+cc)*4096 + p0 + px]);
  }
  __syncthreads();
  #pragma unroll
  for (int it=0; it<4; ++it){
    int idx = it*256 + tid; int pp = idx>>4, c4 = (idx&15)*4;
    u16x4 o;
    #pragma unroll
    for (int u=0;u<4;++u) o[u] = tile[(c4+u)*65 + pp];
    int gc = c0 + c4;
    *(u16x4*)&XT[((long)(gc>>5)*npix + (bl*4096 + p0 + pp))*32 + (gc&31)] = o;
  }
  if (ct == 0){
    int px = tid>>2, cb = (tid&3)*16;
    long gp = bl*4096 + p0 + px;
    #pragma unroll
    for (int half=0; half<2; ++half){
      u16x8 o;
      #pragma unroll
      for (int u=0;u<8;++u){
        int c = cb + half*8 + u;
        o[u] = (c < 4) ? f2b(pos[(long)c*4096 + p0 + px]) : (u16)0;
      }
      int gc = 256 + cb + half*8;
      *(u16x8*)&XT[((long)(gc>>5)*npix + gp)*32 + (gc&31)] = o;
    }
  }
}

// ---------------------------------------------------------------------------
// QKV GEMM: M=1536 (oc), N=CB*4096 (px), K=320.  128x128 tile, 4 waves,
// 64 KiB LDS, 2 blocks/CU.  10 BK=32 phases, 4-deep circular buffer,
// prefetch distance 3, counted vmcnt (8/4/0) -- R8 schedule verbatim.
// R9: staging sources are k-tiled panels (8 KB contiguous per operand per
// phase); each g2lds call = 1 KB = 8 full aligned 128-B lines.  The per-1KB
// XOR source-permute (rule 21 both-sides involution) and ALL reads/MFMA/
// epilogue are byte-identical to R8.
__global__ __launch_bounds__(256) void k_qkv(
    const u16* __restrict__ XT, const u16* __restrict__ WP,
    const u16* __restrict__ BIAS,
    u16* __restrict__ Qb, u16* __restrict__ Kb, u16* __restrict__ Vb,
    int nwg, int npix){
  __shared__ u16 sm[32768];          // 64 KiB: A 4buf x [128][32] | B same at +16384
  int hw = blockIdx.x;
  int bidx = (hw & 7)*(nwg >> 3) + (hw >> 3);   // nwg % 8 == 0 (384*CB)
  int mt = bidx % 12; long nt = bidx / 12;
  int oc0 = mt*128;
  int bl = (int)(nt >> 5); int pl0 = ((int)nt & 31)*128;
  int tid = threadIdx.x;
  int wid = tid>>6, lane = tid&63, l16 = lane&15, qd = lane>>4;
  int wm = wid>>1, wn = wid&1;
  const u16* gA = WP + (long)oc0*32;            // + t*49152 per phase
  const u16* gB = XT + (long)nt*128*32;         // + t*npix*32 per phase

  // source pre-swizzle: LDS chunk l holds global chunk lanez(l)
  // (involution of read-side byte^=(row&7)<<4).
  int b2=(lane>>2)&1, b3=(lane>>3)&1, b4=(lane>>4)&1;
  int lanez = lane ^ ((b2^b4) | (b3<<1) | (b4<<2));

  f32x4 zf = {0.f,0.f,0.f,0.f};
  f32x4 acc[4][4];
  #pragma unroll
  for (int i=0;i<4;++i){
    #pragma unroll
    for (int j=0;j<4;++j) acc[i][j] = zf;
  }

  // stage one contiguous 8-KB panel (2 x 1KB calls per wave).
  auto stageA = [&](int t, int buf){
    const u16* g = gA + (long)t*49152;
    g2lds16(g + wid*512 + lanez*8,        &sm[buf*4096 + wid*512]);
    g2lds16(g + 2048 + wid*512 + lanez*8, &sm[buf*4096 + 2048 + wid*512]);
  };
  auto stageB = [&](int t, int buf){
    const u16* g = gB + (long)t*npix*32;
    g2lds16(g + wid*512 + lanez*8,        &sm[16384 + buf*4096 + wid*512]);
    g2lds16(g + 2048 + wid*512 + lanez*8, &sm[16384 + buf*4096 + 2048 + wid*512]);
  };
  // swizzled read: logical (row, qd) -> u16 index within an 8 KB subtile
  auto swz = [&](int row, int q){ int byt = (row*64 + q*16) ^ ((row&7)<<4); return byt>>1; };

  bf16x8 rA[4], rB[4];
  auto ldA4 = [&](int buf){
    int o = buf*4096;
    #pragma unroll
    for (int i=0;i<4;++i) rA[i] = ldb8(&sm[o + swz(wm*64 + i*16 + l16, qd)]);
  };
  auto ldB4 = [&](int buf){
    int o = 16384 + buf*4096;
    #pragma unroll
    for (int i=0;i<4;++i) rB[i] = ldb8(&sm[o + swz(wn*64 + i*16 + l16, qd)]);
  };
  auto mmac = [&](){
    __builtin_amdgcn_s_setprio(1);
    #pragma unroll
    for (int i=0;i<4;++i){
      #pragma unroll
      for (int j=0;j<4;++j)
        acc[i][j] = MFMA16(rA[i], rB[j], acc[i][j]);
    }
    __builtin_amdgcn_s_setprio(0);
  };

  // prologue: stage phases 0,1,2 (12 vm-ops/thread in flight).
  stageA(0, 0); stageB(0, 0);
  stageA(1, 1); stageB(1, 1);
  stageA(2, 2); stageB(2, 2);

  #pragma unroll
  for (int p=0; p<10; ++p){
    if (p < 8) { VMC8; } else if (p == 8) { VMC4; } else { VMC0; }
    BAR;
    ldA4(p&3); ldB4(p&3);
    if (p < 7){ stageA(p+3, (p+3)&3); stageB(p+3, (p+3)&3); }
    mmac();
  }

  // ---- epilogue: Q, K, V direct u16x4 [p][d] stores ----
  u16* dstb = (oc0 < 512) ? Qb : (oc0 < 1024 ? Kb : Vb);
  #pragma unroll
  for (int mi=0;mi<4;++mi){
    int oc = oc0 + wm*64 + mi*16 + qd*4;
    int ocm = oc & 511;
    int hh = ocm>>6, dd = ocm&63;
    float bv4[4];
    #pragma unroll
    for (int r=0;r<4;++r) bv4[r] = b2f(BIAS[oc + r]);
    #pragma unroll
    for (int ni=0;ni<4;++ni){
      int pl = pl0 + wn*64 + ni*16 + l16;
      u16x4 pk;
      #pragma unroll
      for (int r=0;r<4;++r) pk[r] = f2b(acc[mi][ni][r] + bv4[r]);
      *(u16x4*)&dstb[((long)(bl*8+hh)*4096 + pl)*64 + dd] = pk;
    }
  }
}

// ---------------------------------------------------------------------------
// Axial attention pass.  COL=0: rows (block (bl,h,i)), writes unnormalized
// U + fp32 m,l.  COL=1: cols (block (bl,h,j)), local stats in-register,
// flash-merges with row results, overwrites U with final A.
// V is [p][d] (same layout as Q/K): staged with the SAME gqk address and
// transposed into VT[d][k] via scalar writes (k-XOR swizzle both sides).
template<int COL>
__global__ __launch_bounds__(256) void k_attn(
    const u16* __restrict__ Qb, const u16* __restrict__ Kb,
    const u16* __restrict__ Vsrc, u16* __restrict__ U,
    float* __restrict__ M, float* __restrict__ L){
  __shared__ u16 sm[4*64*72];
  u16* Qs = sm;            // [line][d]  stride 72
  u16* Ks = sm + 4608;
  u16* VT = sm + 9216;     // [d][k^swz]
  u16* Ps = sm + 13824;    // [q][k]
  int bid = blockIdx.x;
  int rc = bid&63, h=(bid>>6)&7, bl=bid>>9;
  long plane  = (long)(bl*8+h)*262144;
  long sbase  = (long)(bl*8+h)*4096;
  int tid = threadIdx.x;
  #pragma unroll
  for (int it=0; it<2; ++it){
    int idx = it*256 + tid; int row = idx>>3, c8 = (idx&7)*8;
    long gqk = plane + ((long)(COL ? (row*64 + rc) : (rc*64 + row)))*64 + c8;
    *(u16x8*)&Qs[row*72 + c8] = *(const u16x8*)&Qb[gqk];
    *(u16x8*)&Ks[row*72 + c8] = *(const u16x8*)&Kb[gqk];
    u16x8 v = *(const u16x8*)&Vsrc[gqk];          // V[pix][d] -- same pattern
    int xr = row ^ ((idx&7)<<3);                  // (d>>3)&7 == idx&7 here
    #pragma unroll
    for (int u=0;u<8;++u) VT[(c8+u)*72 + xr] = v[u];
  }
  __syncthreads();
  int wid = tid>>6, lane = tid&63, l16 = lane&15, qd = lane>>4;
  int j0 = wid*16;
  f32x4 zf = {0.f,0.f,0.f,0.f};
  f32x4 sv[4] = {zf,zf,zf,zf};
  #pragma unroll
  for (int d0=0; d0<64; d0+=32){
    bf16x8 a = ldb8(&Qs[(j0+l16)*72 + d0 + qd*8]);
    #pragma unroll
    for (int n=0;n<4;++n){
      bf16x8 bb = ldb8(&Ks[(n*16+l16)*72 + d0 + qd*8]);
      sv[n] = MFMA16(a, bb, sv[n]);
    }
  }
  const float scale = 0.08838834764831845f;   // 1/sqrt(128)
  float mrow[4], lrow[4];
  #pragma unroll
  for (int r=0;r<4;++r){
    float mv = -1e30f;
    #pragma unroll
    for (int n=0;n<4;++n){ sv[n][r] *= scale; mv = fmaxf(mv, sv[n][r]); }
    mv = fmaxf(mv, __shfl_xor(mv,1)); mv = fmaxf(mv, __shfl_xor(mv,2));
    mv = fmaxf(mv, __shfl_xor(mv,4)); mv = fmaxf(mv, __shfl_xor(mv,8));
    float ls = 0.f;
    #pragma unroll
    for (int n=0;n<4;++n){ float p = expf(fminf(sv[n][r]-mv, 0.f)); sv[n][r] = p; ls += p; }
    ls += __shfl_xor(ls,1); ls += __shfl_xor(ls,2);
    ls += __shfl_xor(ls,4); ls += __shfl_xor(ls,8);
    mrow[r]=mv; lrow[r]=ls;
    int qi = j0 + qd*4 + r;
    #pragma unroll
    for (int n=0;n<4;++n) Ps[qi*72 + n*16 + l16] = f2b(sv[n][r]);
  }
  __syncthreads();
  f32x4 u4[4] = {zf,zf,zf,zf};
  #pragma unroll
  for (int k0=0;k0<64;k0+=32){
    bf16x8 a = ldb8(&Ps[(j0+l16)*72 + k0 + qd*8]);
    #pragma unroll
    for (int n=0;n<4;++n){
      int dd = n*16 + l16;
      bf16x8 bb = ldb8(&VT[dd*72 + ((k0 + qd*8) ^ (((dd>>3)&7)<<3))]);
      u4[n] = MFMA16(a, bb, u4[n]);
    }
  }
  if (!COL){
    #pragma unroll
    for (int r=0;r<4;++r){
      int qi = j0 + qd*4 + r;
      long pl = (long)rc*64 + qi;
      long ob = (sbase + pl)*64;
      #pragma unroll
      for (int n=0;n<4;++n) U[ob + n*16 + l16] = f2b(u4[n][r]);
      if (l16==0){ M[sbase+pl]=mrow[r]; L[sbase+pl]=lrow[r]; }
    }
  } else {
    #pragma unroll
    for (int r=0;r<4;++r){
      int qi = j0 + qd*4 + r;
      long pix = sbase + (long)qi*64 + rc;
      float mw = M[pix], lw = L[pix];
      float mh = mrow[r], lh = lrow[r];
      float m  = fmaxf(mw, mh);
      float ew = expf(fminf(mw - m, 0.f));
      float eh = expf(fminf(mh - m, 0.f));
      float rden = 1.f / fmaxf(ew*lw + eh*lh, 1e-20f);
      long ob = pix*64;
      #pragma unroll
      for (int n=0;n<4;++n){
        float uw = b2f(U[ob + n*16 + l16]);
        U[ob + n*16 + l16] = f2b((ew*uw + eh*u4[n][r])*rden);
      }
    }
  }
}

// ---------------------------------------------------------------------------
// Output projection + residual (round-0 form: single-buffer, no swizzle):
// out = x + Wo @ A + bo.  M=256 (co), N=CB*4096 (px), K=512.
__global__ __launch_bounds__(256) void k_oproj(
    const u16* __restrict__ WoP, const float* __restrict__ bo,
    const u16* __restrict__ AC, const float* __restrict__ x,
    float* __restrict__ out, int b0){
  __shared__ u16 sW[128*32];
  __shared__ u16 sA[128*32];
  int bidx = blockIdx.x;
  int mt = bidx & 1; long nt = bidx >> 1;
  int co0 = mt*128; long p0 = nt*128;
  int bl = (int)(p0>>12), pl0 = (int)(p0&4095);
  int gb = b0 + bl;
  int tid = threadIdx.x;
  int wid=tid>>6, lane=tid&63, l16=lane&15, qd=lane>>4;
  int wm=wid>>1, wn=wid&1;
  int srow = lane>>2, sc8 = (lane&3)*8;
  f32x4 zf = {0.f,0.f,0.f,0.f};
  f32x4 acc[4][4];
  #pragma unroll
  for (int i=0;i<4;++i){
    #pragma unroll
    for (int j=0;j<4;++j) acc[i][j] = zf;
  }
  for (int kk=0; kk<512; kk+=32){
    __syncthreads();
    #pragma unroll
    for (int c=0;c<2;++c){
      int seg = wid*2 + c;
      int row = seg*16 + srow;
      g2lds16(&WoP[(long)(co0+row)*512 + kk + sc8], &sW[seg*512]);
      g2lds16(&AC[((long)(bl*8+(kk>>6))*4096 + pl0 + row)*64 + (kk&63) + sc8], &sA[seg*512]);
    }
    __syncthreads();
    bf16x8 a[4], bb[4];
    #pragma unroll
    for (int mi=0;mi<4;++mi) a[mi]  = ldb8(&sW[(wm*64+mi*16+l16)*32 + qd*8]);
    #pragma unroll
    for (int ni=0;ni<4;++ni) bb[ni] = ldb8(&sA[(wn*64+ni*16+l16)*32 + qd*8]);
    #pragma unroll
    for (int mi=0;mi<4;++mi){
      #pragma unroll
      for (int ni=0;ni<4;++ni)
        acc[mi][ni] = MFMA16(a[mi], bb[ni], acc[mi][ni]);
    }
  }
  #pragma unroll
  for (int mi=0;mi<4;++mi){
    #pragma unroll
    for (int ni=0;ni<4;++ni){
      int n = wn*64+ni*16+l16; int pl = pl0+n;
      #pragma unroll
      for (int r=0;r<4;++r){
        int co = co0 + wm*64+mi*16+qd*4+r;
        long addr = ((long)(gb*256+co))*4096 + pl;
        out[addr] = acc[mi][ni][r] + bo[co] + x[addr];
      }
    }
  }
}

// ---------------------------------------------------------------------------
extern "C" void kernel_launch(void* const* d_in, const int* in_sizes, int n_in,
                              void* d_out, int out_size, void* d_ws, size_t ws_size,
                              hipStream_t stream) {
  (void)in_sizes; (void)n_in; (void)out_size;
  const float* x    = (const float*)d_in[0];
  const float* pos  = (const float*)d_in[1];
  const float* Wk   = (const float*)d_in[2];
  const float* bk   = (const float*)d_in[3];
  const float* Wq   = (const float*)d_in[4];
  const float* bq   = (const float*)d_in[5];
  const float* Wv   = (const float*)d_in[6];
  const float* bv   = (const float*)d_in[7];
  const float* Wo   = (const float*)d_in[8];
  const float* bo   = (const float*)d_in[9];
  float* out = (float*)d_out;
  char* ws = (char*)d_ws;

  // Fixed: WP 983,040 + BIAS 3,072 + WoP 262,144 = 1,248,256 B.
  // Per-batch: XT 2,621,440 + {Q,K,V,U} 4 x 4,194,304 + {M,L} 2 x 131,072
  //          = 19,660,800 B.   (ws >= 273 MB proven -> CB >= 8.)
  const long per_batch = 19660800l;
  const long fixed = 1248256l;
  if (fixed + per_batch > (long)ws_size){
    k_sentinel<<<65536, 256, 0, stream>>>(out);
    return;
  }
  int CB = 16;
  while (CB > 1 && fixed + (long)CB*per_batch > (long)ws_size) CB >>= 1;

  u16*  WP   = (u16*)(ws);
  u16*  BIAS = (u16*)(ws + 983040l);
  u16*  WoP  = (u16*)(ws + 986112l);
  long base  = fixed;
  u16*  XT   = (u16*)(ws + base);
  u16*  Qc   = (u16*)(ws + base + (long)CB*2621440l);
  u16*  Kc   = (u16*)((char*)Qc  + (long)CB*4194304l);
  u16*  Vc   = (u16*)((char*)Kc  + (long)CB*4194304l);
  u16*  Uw   = (u16*)((char*)Vc  + (long)CB*4194304l);
  float* MWc = (float*)((char*)Uw + (long)CB*4194304l);
  float* LWc = (float*)((char*)MWc + (long)CB*131072l);

  k_prep_w<<<1792, 256, 0, stream>>>(Wq, Wk, Wv, bq, bk, bv, Wo, WP, BIAS, WoP);
  for (int b0 = 0; b0 < 16; b0 += CB){
    int npix = CB*4096;
    k_cvtx    <<<CB*256, 256, 0, stream>>>(x, pos, XT, b0, npix);
    k_qkv     <<<CB*384, 256, 0, stream>>>(XT, WP, BIAS, Qc, Kc, Vc, CB*384, npix);
    k_attn<0> <<<CB*512, 256, 0, stream>>>(Qc, Kc, Vc, Uw, MWc, LWc);
    k_attn<1> <<<CB*512, 256, 0, stream>>>(Qc, Kc, Vc, Uw, MWc, LWc);
    k_oproj   <<<CB*64,  256, 0, stream>>>(WoP, bo, Uw, x, out, b0);
  }
}

// Round 11
// 403.827 us; speedup vs baseline: 1.0365x; 1.0365x over previous
//
#include <hip/hip_runtime.h>

typedef unsigned short u16;
typedef __bf16 bf16x8 __attribute__((ext_vector_type(8)));
typedef float f32x4 __attribute__((ext_vector_type(4)));
typedef unsigned short u16x8 __attribute__((ext_vector_type(8)));
typedef unsigned short u16x4 __attribute__((ext_vector_type(4)));

#define MFMA16(A,B,C) __builtin_amdgcn_mfma_f32_16x16x32_bf16(A,B,C,0,0,0)

__device__ __forceinline__ float b2f(u16 h){ unsigned u = ((unsigned)h)<<16; return __builtin_bit_cast(float,u); }
__device__ __forceinline__ u16 f2b(float f){ unsigned u = __builtin_bit_cast(unsigned,f); u += 0x7fffu + ((u>>16)&1u); return (u16)(u>>16); }
__device__ __forceinline__ bf16x8 ldb8(const u16* p){ return __builtin_bit_cast(bf16x8, *(const u16x8*)p); }

// async global->LDS, 16B per lane; LDS dest = wave-uniform base + lane*16.
__device__ __forceinline__ void g2lds16(const u16* g, u16* l){
  __builtin_amdgcn_global_load_lds((const __attribute__((address_space(1))) void*)g,
                                   (__attribute__((address_space(3))) void*)l, 16, 0, 0);
}

#define BAR   __builtin_amdgcn_s_barrier()
#define VMC4  asm volatile("s_waitcnt vmcnt(4)" ::: "memory")
#define VMC0  asm volatile("s_waitcnt vmcnt(0)" ::: "memory")

// B=16, C=256, H=W=64, NH=8, DH=64, POS_C=4.  4096 px/batch.
// fp32 inputs/output; bf16 internal.  CB batches/chunk from ws_size.
// K extended 256->320: cols 256..259 = pos channels, 260..319 = 0, so the
// QKV GEMM absorbs the rank-4 pos correction; K = 5 x BK=64 tiles.
// Layouts: XT [p][320] bf16; Q,K,V ALL [bl][h][p][d]; U [bl][h][p][d].
// V^T is built per-plane-slice inside k_attn (V staging address == Q/K's).
// R11: R6-champion config restored verbatim (qkv parked at its ~62us
// structural plateau after 6 refuted variants); attn gains s_setprio
// around MFMA clusters (m191 regime: independent blocks, 4/CU resident,
// +4-7%) and exp2f softmax (v_exp_f32 is exp2; drops libm range-reduction).

// ---------------------------------------------------------------------------
// Weight prep: WP[1536][320] (cols 256..259 = pos weights, 260..319 = 0),
// BIAS[1536], WoP[256][512] (bf16).
__global__ void k_prep_w(const float* __restrict__ Wq, const float* __restrict__ Wk,
                         const float* __restrict__ Wv, const float* __restrict__ bq,
                         const float* __restrict__ bk, const float* __restrict__ bv,
                         const float* __restrict__ Wo,
                         u16* __restrict__ WP, u16* __restrict__ BIAS,
                         u16* __restrict__ WoP){
  int r = blockIdx.x;                 // 0..1791
  int tid = threadIdx.x;
  if (r < 1536){
    int t = r >> 9, rm = r & 511;
    const float* src = (t==0 ? Wq : (t==1 ? Wk : Wv)) + (long)rm*260;
    WP[(long)r*320 + tid] = f2b(src[tid]);
    if (tid < 64) WP[(long)r*320 + 256 + tid] = (tid < 4) ? f2b(src[256 + tid]) : (u16)0;
    if (tid == 0){
      const float* bs = (t==0 ? bq : (t==1 ? bk : bv));
      BIAS[r] = f2b(bs[rm]);
    }
  } else {
    int co = r - 1536;
    WoP[(long)co*512 + tid]       = f2b(Wo[(long)co*512 + tid]);
    WoP[(long)co*512 + 256 + tid] = f2b(Wo[(long)co*512 + 256 + tid]);
  }
}

// Diagnostic: ws too small -> fill out with 100.0f.
__global__ void k_sentinel(float* __restrict__ out){
  long i = (long)blockIdx.x*256 + threadIdx.x;
  out[i] = 100.0f;
}

// ---------------------------------------------------------------------------
// x [gb][c][4096] fp32 -> XT [bl*4096+p][320] bf16 (transpose + convert).
// ct==0 blocks also write the pos tail: cols 256..259 = pos, 260..319 = 0.
__global__ __launch_bounds__(256) void k_cvtx(const float* __restrict__ x,
                                              const float* __restrict__ pos,
                                              u16* __restrict__ XT, int b0){
  __shared__ u16 tile[64*65];
  int bidx = blockIdx.x;
  int ct = bidx & 3, pt = (bidx>>2)&63, bl = bidx>>8;
  int c0 = ct*64, p0 = pt*64;
  int tid = threadIdx.x;
  const float* xb = x + (long)(b0+bl)*256*4096;
  #pragma unroll
  for (int it=0; it<16; ++it){
    int idx = it*256 + tid; int cc = idx>>6, px = idx&63;
    tile[cc*65 + px] = f2b(xb[(long)(c0+cc)*4096 + p0 + px]);
  }
  __syncthreads();
  u16* dst = XT + ((long)(bl*4096 + p0))*320 + c0;
  #pragma unroll
  for (int it=0; it<4; ++it){
    int idx = it*256 + tid; int pp = idx>>4, c4 = (idx&15)*4;
    u16x4 o;
    #pragma unroll
    for (int u=0;u<4;++u) o[u] = tile[(c4+u)*65 + pp];
    *(u16x4*)&dst[(long)pp*320 + c4] = o;
  }
  if (ct == 0){
    int px = tid>>2, cb = (tid&3)*16;
    u16* row = XT + ((long)(bl*4096 + p0 + px))*320 + 256 + cb;
    #pragma unroll
    for (int half=0; half<2; ++half){
      u16x8 o;
      #pragma unroll
      for (int u=0;u<8;++u){
        int c = cb + half*8 + u;
        o[u] = (c < 4) ? f2b(pos[(long)c*4096 + p0 + px]) : (u16)0;
      }
      *(u16x8*)&row[half*8] = o;
    }
  }
}

// ---------------------------------------------------------------------------
// QKV GEMM: M=1536 (oc), N=CB*4096 (px), K=320.  128x128 tile, BK=64
// (two [ks][128][32] subtiles), 4 waves (2Mx2N), 64 KiB LDS, 2 blocks/CU.
// Schedule per K-tile (R6-measured champion): 2 phases {ds_read frags(cur)
// || stage both ks-half subtiles(t+1) || BAR || 16 MFMA (setprio) || VMC4
// || BAR}.  vmcnt(4) after every phase; never 0 until the final tile.
// 8-row XOR swizzle both sides (R4-verified: conflicts 19.5M -> 2.9M).
__global__ __launch_bounds__(256) void k_qkv(
    const u16* __restrict__ XT, const u16* __restrict__ WP,
    const u16* __restrict__ BIAS,
    u16* __restrict__ Qb, u16* __restrict__ Kb, u16* __restrict__ Vb, int nwg){
  __shared__ u16 sm[32768];          // 64 KiB: A 2buf x 2ks x [128][32] | B same at +16384
  int hw = blockIdx.x;
  int bidx = (hw & 7)*(nwg >> 3) + (hw >> 3);   // nwg % 8 == 0 (384*CB)
  int mt = bidx % 12; long nt = bidx / 12;
  int oc0 = mt*128;
  int bl = (int)(nt >> 5); int pl0 = ((int)nt & 31)*128;
  int tid = threadIdx.x;
  int wid = tid>>6, lane = tid&63, l16 = lane&15, qd = lane>>4;
  int wm = wid>>1, wn = wid&1;
  const u16* gA = WP + (long)oc0*320;
  const u16* gB = XT + ((long)nt*128)*320;

  // source pre-swizzle: lane (= physical 16B chunk) fetches logical chunk
  // l = lane ^ ((b2^b4)|(b3<<1)|(b4<<2))  (involution of byte^=(row&7)<<4).
  int b2=(lane>>2)&1, b3=(lane>>3)&1, b4=(lane>>4)&1;
  int lanez = lane ^ ((b2^b4) | (b3<<1) | (b4<<2));
  int srowz = lanez>>2, scolz = (lanez&3)*8;

  f32x4 zf = {0.f,0.f,0.f,0.f};
  f32x4 acc[4][4];
  #pragma unroll
  for (int i=0;i<4;++i){
    #pragma unroll
    for (int j=0;j<4;++j) acc[i][j] = zf;
  }

  // stage one [128][32] subtile (8 KB = 2 x 4KB calls); 4 waves cover
  // rows 0..63 (call 1) and 64..127 (call 2).
  auto stage2 = [&](const u16* g, int ldsOff){
    g2lds16(g + (long)(wid*16 + srowz)*320 + scolz,       &sm[ldsOff + wid*512]);
    g2lds16(g + (long)(64 + wid*16 + srowz)*320 + scolz,  &sm[ldsOff + 2048 + wid*512]);
  };
  auto aOff = [&](int buf,int ks){ return (buf*2+ks)*4096; };
  auto bOff = [&](int buf,int ks){ return 16384 + (buf*2+ks)*4096; };
  // swizzled read: logical (row, qd) -> u16 index
  auto swz = [&](int row, int q){ int byt = (row*64 + q*16) ^ ((row&7)<<4); return byt>>1; };

  bf16x8 rA[4], rB[4];
  auto ldA4 = [&](int buf,int ks){
    int o = aOff(buf,ks);
    #pragma unroll
    for (int i=0;i<4;++i) rA[i] = ldb8(&sm[o + swz(wm*64 + i*16 + l16, qd)]);
  };
  auto ldB4 = [&](int buf,int ks){
    int o = bOff(buf,ks);
    #pragma unroll
    for (int i=0;i<4;++i) rB[i] = ldb8(&sm[o + swz(wn*64 + i*16 + l16, qd)]);
  };
  auto mmac = [&](){
    __builtin_amdgcn_s_setprio(1);
    #pragma unroll
    for (int i=0;i<4;++i){
      #pragma unroll
      for (int j=0;j<4;++j)
        acc[i][j] = MFMA16(rA[i], rB[j], acc[i][j]);
    }
    __builtin_amdgcn_s_setprio(0);
  };

  // prologue: tile0 all 4 subtiles -> buf0 (8 vm-ops/thread).
  // VMC4 -> A0,B0 (oldest 4) landed; A1,B1 still in flight.
  stage2(gA + 0,  aOff(0,0));
  stage2(gB + 0,  bOff(0,0));
  stage2(gA + 32, aOff(0,1));
  stage2(gB + 32, bOff(0,1));
  VMC4; BAR;

  for (int t=0; t<5; ++t){
    int cur = t&1, nxt = cur^1;
    bool st = (t < 4);
    int k1 = (t+1)*64;
    // ph0: ks0
    ldA4(cur,0); ldB4(cur,0);
    if (st){ stage2(gA + k1, aOff(nxt,0)); stage2(gB + k1, bOff(nxt,0)); }
    BAR; mmac();
    if (st) { VMC4; } else { VMC0; }   // drain prev-phase stages (final: A1,B1 cur)
    BAR;
    // ph1: ks1
    ldA4(cur,1); ldB4(cur,1);
    if (st){ stage2(gA + k1 + 32, aOff(nxt,1)); stage2(gB + k1 + 32, bOff(nxt,1)); }
    BAR; mmac();
    if (st) VMC4;                       // final tile: nothing outstanding
    BAR;
  }

  // ---- epilogue: Q, K, V direct u16x4 [p][d] stores ----
  u16* dstb = (oc0 < 512) ? Qb : (oc0 < 1024 ? Kb : Vb);
  #pragma unroll
  for (int mi=0;mi<4;++mi){
    int oc = oc0 + wm*64 + mi*16 + qd*4;
    int ocm = oc & 511;
    int hh = ocm>>6, dd = ocm&63;
    float bv4[4];
    #pragma unroll
    for (int r=0;r<4;++r) bv4[r] = b2f(BIAS[oc + r]);
    #pragma unroll
    for (int ni=0;ni<4;++ni){
      int pl = pl0 + wn*64 + ni*16 + l16;
      u16x4 pk;
      #pragma unroll
      for (int r=0;r<4;++r) pk[r] = f2b(acc[mi][ni][r] + bv4[r]);
      *(u16x4*)&dstb[((long)(bl*8+hh)*4096 + pl)*64 + dd] = pk;
    }
  }
}

// ---------------------------------------------------------------------------
// Axial attention pass.  COL=0: rows (block (bl,h,i)), writes unnormalized
// U + fp32 m,l.  COL=1: cols (block (bl,h,j)), local stats in-register,
// flash-merges with row results, overwrites U with final A.
// V is [p][d] (same layout as Q/K): staged with the SAME gqk address and
// transposed into VT[d][k] via scalar writes (k-XOR swizzle both sides).
// R11: setprio(1) around MFMA clusters (m191 regime: independent blocks,
// 4/CU resident); exp2f softmax with log2e folded (v_exp_f32 is exp2).
template<int COL>
__global__ __launch_bounds__(256) void k_attn(
    const u16* __restrict__ Qb, const u16* __restrict__ Kb,
    const u16* __restrict__ Vsrc, u16* __restrict__ U,
    float* __restrict__ M, float* __restrict__ L){
  __shared__ u16 sm[4*64*72];
  u16* Qs = sm;            // [line][d]  stride 72
  u16* Ks = sm + 4608;
  u16* VT = sm + 9216;     // [d][k^swz]
  u16* Ps = sm + 13824;    // [q][k]
  int bid = blockIdx.x;
  int rc = bid&63, h=(bid>>6)&7, bl=bid>>9;
  long plane  = (long)(bl*8+h)*262144;
  long sbase  = (long)(bl*8+h)*4096;
  int tid = threadIdx.x;
  #pragma unroll
  for (int it=0; it<2; ++it){
    int idx = it*256 + tid; int row = idx>>3, c8 = (idx&7)*8;
    long gqk = plane + ((long)(COL ? (row*64 + rc) : (rc*64 + row)))*64 + c8;
    *(u16x8*)&Qs[row*72 + c8] = *(const u16x8*)&Qb[gqk];
    *(u16x8*)&Ks[row*72 + c8] = *(const u16x8*)&Kb[gqk];
    u16x8 v = *(const u16x8*)&Vsrc[gqk];          // V[pix][d] -- same pattern
    int xr = row ^ ((idx&7)<<3);                  // (d>>3)&7 == idx&7 here
    #pragma unroll
    for (int u=0;u<8;++u) VT[(c8+u)*72 + xr] = v[u];
  }
  __syncthreads();
  int wid = tid>>6, lane = tid&63, l16 = lane&15, qd = lane>>4;
  int j0 = wid*16;
  f32x4 zf = {0.f,0.f,0.f,0.f};
  f32x4 sv[4] = {zf,zf,zf,zf};
  __builtin_amdgcn_s_setprio(1);
  #pragma unroll
  for (int d0=0; d0<64; d0+=32){
    bf16x8 a = ldb8(&Qs[(j0+l16)*72 + d0 + qd*8]);
    #pragma unroll
    for (int n=0;n<4;++n){
      bf16x8 bb = ldb8(&Ks[(n*16+l16)*72 + d0 + qd*8]);
      sv[n] = MFMA16(a, bb, sv[n]);
    }
  }
  __builtin_amdgcn_s_setprio(0);
  const float scale = 0.08838834764831845f;   // 1/sqrt(128)
  const float LOG2E = 1.4426950408889634f;
  float mrow[4], lrow[4];
  #pragma unroll
  for (int r=0;r<4;++r){
    float mv = -1e30f;
    #pragma unroll
    for (int n=0;n<4;++n){ sv[n][r] *= scale; mv = fmaxf(mv, sv[n][r]); }
    mv = fmaxf(mv, __shfl_xor(mv,1)); mv = fmaxf(mv, __shfl_xor(mv,2));
    mv = fmaxf(mv, __shfl_xor(mv,4)); mv = fmaxf(mv, __shfl_xor(mv,8));
    float ls = 0.f;
    #pragma unroll
    for (int n=0;n<4;++n){
      float p = exp2f(fminf(sv[n][r]-mv, 0.f)*LOG2E);
      sv[n][r] = p; ls += p;
    }
    ls += __shfl_xor(ls,1); ls += __shfl_xor(ls,2);
    ls += __shfl_xor(ls,4); ls += __shfl_xor(ls,8);
    mrow[r]=mv; lrow[r]=ls;
    int qi = j0 + qd*4 + r;
    #pragma unroll
    for (int n=0;n<4;++n) Ps[qi*72 + n*16 + l16] = f2b(sv[n][r]);
  }
  __syncthreads();
  f32x4 u4[4] = {zf,zf,zf,zf};
  __builtin_amdgcn_s_setprio(1);
  #pragma unroll
  for (int k0=0;k0<64;k0+=32){
    bf16x8 a = ldb8(&Ps[(j0+l16)*72 + k0 + qd*8]);
    #pragma unroll
    for (int n=0;n<4;++n){
      int dd = n*16 + l16;
      bf16x8 bb = ldb8(&VT[dd*72 + ((k0 + qd*8) ^ (((dd>>3)&7)<<3))]);
      u4[n] = MFMA16(a, bb, u4[n]);
    }
  }
  __builtin_amdgcn_s_setprio(0);
  if (!COL){
    #pragma unroll
    for (int r=0;r<4;++r){
      int qi = j0 + qd*4 + r;
      long pl = (long)rc*64 + qi;
      long ob = (sbase + pl)*64;
      #pragma unroll
      for (int n=0;n<4;++n) U[ob + n*16 + l16] = f2b(u4[n][r]);
      if (l16==0){ M[sbase+pl]=mrow[r]; L[sbase+pl]=lrow[r]; }
    }
  } else {
    #pragma unroll
    for (int r=0;r<4;++r){
      int qi = j0 + qd*4 + r;
      long pix = sbase + (long)qi*64 + rc;
      float mw = M[pix], lw = L[pix];
      float mh = mrow[r], lh = lrow[r];
      float m  = fmaxf(mw, mh);
      float ew = exp2f(fminf(mw - m, 0.f)*LOG2E);
      float eh = exp2f(fminf(mh - m, 0.f)*LOG2E);
      float rden = 1.f / fmaxf(ew*lw + eh*lh, 1e-20f);
      long ob = pix*64;
      #pragma unroll
      for (int n=0;n<4;++n){
        float uw = b2f(U[ob + n*16 + l16]);
        U[ob + n*16 + l16] = f2b((ew*uw + eh*u4[n][r])*rden);
      }
    }
  }
}

// ---------------------------------------------------------------------------
// Output projection + residual (round-0 form: single-buffer, no swizzle):
// out = x + Wo @ A + bo.  M=256 (co), N=CB*4096 (px), K=512.
__global__ __launch_bounds__(256) void k_oproj(
    const u16* __restrict__ WoP, const float* __restrict__ bo,
    const u16* __restrict__ AC, const float* __restrict__ x,
    float* __restrict__ out, int b0){
  __shared__ u16 sW[128*32];
  __shared__ u16 sA[128*32];
  int bidx = blockIdx.x;
  int mt = bidx & 1; long nt = bidx >> 1;
  int co0 = mt*128; long p0 = nt*128;
  int bl = (int)(p0>>12), pl0 = (int)(p0&4095);
  int gb = b0 + bl;
  int tid = threadIdx.x;
  int wid=tid>>6, lane=tid&63, l16=lane&15, qd=lane>>4;
  int wm=wid>>1, wn=wid&1;
  int srow = lane>>2, sc8 = (lane&3)*8;
  f32x4 zf = {0.f,0.f,0.f,0.f};
  f32x4 acc[4][4];
  #pragma unroll
  for (int i=0;i<4;++i){
    #pragma unroll
    for (int j=0;j<4;++j) acc[i][j] = zf;
  }
  for (int kk=0; kk<512; kk+=32){
    __syncthreads();
    #pragma unroll
    for (int c=0;c<2;++c){
      int seg = wid*2 + c;
      int row = seg*16 + srow;
      g2lds16(&WoP[(long)(co0+row)*512 + kk + sc8], &sW[seg*512]);
      g2lds16(&AC[((long)(bl*8+(kk>>6))*4096 + pl0 + row)*64 + (kk&63) + sc8], &sA[seg*512]);
    }
    __syncthreads();
    bf16x8 a[4], bb[4];
    #pragma unroll
    for (int mi=0;mi<4;++mi) a[mi]  = ldb8(&sW[(wm*64+mi*16+l16)*32 + qd*8]);
    #pragma unroll
    for (int ni=0;ni<4;++ni) bb[ni] = ldb8(&sA[(wn*64+ni*16+l16)*32 + qd*8]);
    #pragma unroll
    for (int mi=0;mi<4;++mi){
      #pragma unroll
      for (int ni=0;ni<4;++ni)
        acc[mi][ni] = MFMA16(a[mi], bb[ni], acc[mi][ni]);
    }
  }
  #pragma unroll
  for (int mi=0;mi<4;++mi){
    #pragma unroll
    for (int ni=0;ni<4;++ni){
      int n = wn*64+ni*16+l16; int pl = pl0+n;
      #pragma unroll
      for (int r=0;r<4;++r){
        int co = co0 + wm*64+mi*16+qd*4+r;
        long addr = ((long)(gb*256+co))*4096 + pl;
        out[addr] = acc[mi][ni][r] + bo[co] + x[addr];
      }
    }
  }
}

// ---------------------------------------------------------------------------
extern "C" void kernel_launch(void* const* d_in, const int* in_sizes, int n_in,
                              void* d_out, int out_size, void* d_ws, size_t ws_size,
                              hipStream_t stream) {
  (void)in_sizes; (void)n_in; (void)out_size;
  const float* x    = (const float*)d_in[0];
  const float* pos  = (const float*)d_in[1];
  const float* Wk   = (const float*)d_in[2];
  const float* bk   = (const float*)d_in[3];
  const float* Wq   = (const float*)d_in[4];
  const float* bq   = (const float*)d_in[5];
  const float* Wv   = (const float*)d_in[6];
  const float* bv   = (const float*)d_in[7];
  const float* Wo   = (const float*)d_in[8];
  const float* bo   = (const float*)d_in[9];
  float* out = (float*)d_out;
  char* ws = (char*)d_ws;

  // Fixed: WP 983,040 + BIAS 3,072 + WoP 262,144 = 1,248,256 B.
  // Per-batch: XT 2,621,440 + {Q,K,V,U} 4 x 4,194,304 + {M,L} 2 x 131,072
  //          = 19,660,800 B.   (ws >= 273 MB proven -> CB >= 8.)
  const long per_batch = 19660800l;
  const long fixed = 1248256l;
  if (fixed + per_batch > (long)ws_size){
    k_sentinel<<<65536, 256, 0, stream>>>(out);
    return;
  }
  int CB = 16;
  while (CB > 1 && fixed + (long)CB*per_batch > (long)ws_size) CB >>= 1;

  u16*  WP   = (u16*)(ws);
  u16*  BIAS = (u16*)(ws + 983040l);
  u16*  WoP  = (u16*)(ws + 986112l);
  long base  = fixed;
  u16*  XT   = (u16*)(ws + base);
  u16*  Qc   = (u16*)(ws + base + (long)CB*2621440l);
  u16*  Kc   = (u16*)((char*)Qc  + (long)CB*4194304l);
  u16*  Vc   = (u16*)((char*)Kc  + (long)CB*4194304l);
  u16*  Uw   = (u16*)((char*)Vc  + (long)CB*4194304l);
  float* MWc = (float*)((char*)Uw + (long)CB*4194304l);
  float* LWc = (float*)((char*)MWc + (long)CB*131072l);

  k_prep_w<<<1792, 256, 0, stream>>>(Wq, Wk, Wv, bq, bk, bv, Wo, WP, BIAS, WoP);
  for (int b0 = 0; b0 < 16; b0 += CB){
    k_cvtx    <<<CB*256, 256, 0, stream>>>(x, pos, XT, b0);
    k_qkv     <<<CB*384, 256, 0, stream>>>(XT, WP, BIAS, Qc, Kc, Vc, CB*384);
    k_attn<0> <<<CB*512, 256, 0, stream>>>(Qc, Kc, Vc, Uw, MWc, LWc);
    k_attn<1> <<<CB*512, 256, 0, stream>>>(Qc, Kc, Vc, Uw, MWc, LWc);
    k_oproj   <<<CB*64,  256, 0, stream>>>(WoP, bo, Uw, x, out, b0);
  }
}